// Round 1
// baseline (21196.252 us; speedup 1.0000x reference)
//
#include <hip/hip_runtime.h>
#include <hip/hip_bf16.h>
#include <math.h>

// xLSTM forward on MI355X (gfx950).
// Layout conventions (internal): activation rows are time-major r = s*16 + b,
// H=1024 contiguous. h sequences stored [slot][b][1024] bf16 where slot s holds
// h[s-1] (slot 0 = zeros). Gates per step: [16, 4096] with i|f|z|o at
// j, j+1024, j+2048, j+3072 -> each wave owns 16 h-columns across all 4 gates,
// so c-state is wave-local.

typedef __bf16 bf16x8 __attribute__((ext_vector_type(8)));
typedef __bf16 bf16x4 __attribute__((ext_vector_type(4)));
typedef float floatx4 __attribute__((ext_vector_type(4)));

__device__ __forceinline__ float sigmf(float x){ return 1.0f/(1.0f+expf(-x)); }

// ---------- f32 -> bf16 weight conversion (4 elems/thread) ----------
__global__ __launch_bounds__(256) void cvt_kernel(const float* __restrict__ src,
                                                  __bf16* __restrict__ dst, int n4){
  int i = blockIdx.x*256 + threadIdx.x;
  if (i >= n4) return;
  float4 v = ((const float4*)src)[i];
  bf16x4 o = { (__bf16)v.x, (__bf16)v.y, (__bf16)v.z, (__bf16)v.w };
  ((bf16x4*)dst)[i] = o;
}

// ---------- embedding gather: x[s*16+b][:] = emb[seq[b][s]][:] ----------
__global__ __launch_bounds__(256) void gather_kernel(const int* __restrict__ seq,
    const float* __restrict__ emb, float* __restrict__ x, __bf16* __restrict__ xbf){
  int r = blockIdx.x;                 // 0..4095, s = r>>4, b = r&15
  int tid = threadIdx.x;
  int tok = seq[((r&15)<<8) + (r>>4)];
  float4 v = *(const float4*)(emb + (size_t)tok*1024 + (tid<<2));
  *(float4*)(x + ((size_t)r<<10) + (tid<<2)) = v;
  bf16x4 o = { (__bf16)v.x, (__bf16)v.y, (__bf16)v.z, (__bf16)v.w };
  *(bf16x4*)(xbf + ((size_t)r<<10) + (tid<<2)) = o;
}

// ---------- generic bf16 MFMA GEMM: C[M=4096, N] = A[4096,1024] @ B[N,1024]^T ----------
// mode 0: out = acc + bias[col]                       (f32, row-major)
// mode 1: out = gelu_exact(acc + bias[col])           (f32, row-major)
// mode 2: out[(b*256+s)*N + col] = acc + bias[col]    (logits, [B,S,V] remap)
__global__ __launch_bounds__(256) void gemm_kernel(const __bf16* __restrict__ A,
    const __bf16* __restrict__ Bw, const float* __restrict__ bias,
    float* __restrict__ out, int N, int mode){
  const int K = 1024;
  __shared__ __align__(16) __bf16 As[64][40];   // +8 pad -> 80B row stride, 2-way max
  __shared__ __align__(16) __bf16 Bs[64][40];
  int m0 = blockIdx.y<<6, n0 = blockIdx.x<<6;
  int tid = threadIdx.x, w = tid>>6, lane = tid&63, quad = lane>>4, ln = lane&15;
  int lrow = tid>>2, lcg = (tid&3)<<3;
  const __bf16* ag = A  + (size_t)(m0+lrow)*K + lcg;
  const __bf16* bg = Bw + (size_t)(n0+lrow)*K + lcg;
  floatx4 acc[4] = {{0.f,0.f,0.f,0.f},{0.f,0.f,0.f,0.f},{0.f,0.f,0.f,0.f},{0.f,0.f,0.f,0.f}};
  for (int kk = 0; kk < K; kk += 32){
    uint4 av = *(const uint4*)(ag + kk);
    uint4 bv = *(const uint4*)(bg + kk);
    __syncthreads();
    *(uint4*)&As[lrow][lcg] = av;
    *(uint4*)&Bs[lrow][lcg] = bv;
    __syncthreads();
    bf16x8 af = *(const bf16x8*)&As[(w<<4)+ln][quad<<3];
#pragma unroll
    for (int nt = 0; nt < 4; nt++){
      bf16x8 bf_ = *(const bf16x8*)&Bs[(nt<<4)+ln][quad<<3];
      acc[nt] = __builtin_amdgcn_mfma_f32_16x16x32_bf16(af, bf_, acc[nt], 0, 0, 0);
    }
  }
#pragma unroll
  for (int nt = 0; nt < 4; nt++){
    int col = n0 + (nt<<4) + ln;
    float bv = bias[col];
#pragma unroll
    for (int r = 0; r < 4; r++){
      int row = m0 + (w<<4) + (quad<<2) + r;   // D layout: row = quad*4+reg, col = lane&15
      float v = acc[nt][r] + bv;
      if (mode == 1) v = 0.5f*v*(1.0f + erff(v*0.70710678118f));
      size_t oidx;
      if (mode == 2){ int s = row>>4, b = row&15; oidx = ((size_t)((b<<8)+s))*N + col; }
      else oidx = (size_t)row*N + col;
      out[oidx] = v;
    }
  }
}

// ---------- recurrence tick: layer0 at t, layer1 at t-1 (pipelined) ----------
// 32 blocks x 4 waves = 128 waves. wid<64: layer0 h-tile; wid>=64: layer1 h-tile.
__global__ __launch_bounds__(256) void tick_kernel(
    const __bf16* __restrict__ Whh0, const __bf16* __restrict__ Wih1,
    const __bf16* __restrict__ Whh1, const float* __restrict__ bg1,
    const float* __restrict__ ih, __bf16* __restrict__ h0seq, __bf16* __restrict__ h1seq,
    float* __restrict__ c0, float* __restrict__ c1, int t){
  int wid  = (blockIdx.x<<2) + (threadIdx.x>>6);
  int lane = threadIdx.x&63, quad = lane>>4, ln = lane&15;
  if (wid < 64){
    if (t >= 256) return;
    int j0 = wid<<4;
    floatx4 acc[4];
#pragma unroll
    for (int g = 0; g < 4; g++)
#pragma unroll
      for (int r = 0; r < 4; r++)
        acc[g][r] = ih[((size_t)(t*16) + (quad<<2)+r)*4096 + (g<<10) + j0 + ln];
    const __bf16* hp = h0seq + ((size_t)t<<14);     // h0[t-1]
#pragma unroll 2
    for (int k0 = 0; k0 < 1024; k0 += 32){
      bf16x8 a = *(const bf16x8*)(hp + ((size_t)ln<<10) + k0 + (quad<<3));
#pragma unroll
      for (int g = 0; g < 4; g++){
        bf16x8 b = *(const bf16x8*)(Whh0 + (size_t)((g<<10)+j0+ln)*1024 + k0 + (quad<<3));
        acc[g] = __builtin_amdgcn_mfma_f32_16x16x32_bf16(a, b, acc[g], 0, 0, 0);
      }
    }
#pragma unroll
    for (int r = 0; r < 4; r++){
      int brow = (quad<<2)+r, j = j0+ln, ci = (brow<<10)+j;
      float i_ = acc[0][r], f_ = acc[1][r], z_ = acc[2][r], o_ = acc[3][r];
      float cp = c0[ci];
      float cn = sigmf(f_)*cp + expf(i_)*tanhf(z_);
      float hn = sigmf(o_)*tanhf(cn);
      c0[ci] = cn;
      h0seq[((size_t)(t+1)<<14) + ci] = (__bf16)hn;
    }
  } else {
    if (t < 1) return;
    int t1 = t-1, j0 = (wid-64)<<4;
    floatx4 acc[4];
#pragma unroll
    for (int g = 0; g < 4; g++){
      float bv = bg1[(g<<10)+j0+ln];
      acc[g] = (floatx4){bv, bv, bv, bv};
    }
    const __bf16* ha = h0seq + ((size_t)(t1+1)<<14);  // h0[t1]
    const __bf16* hb = h1seq + ((size_t)t1<<14);      // h1[t1-1]
#pragma unroll 2
    for (int k0 = 0; k0 < 1024; k0 += 32){
      bf16x8 a0 = *(const bf16x8*)(ha + ((size_t)ln<<10) + k0 + (quad<<3));
      bf16x8 a1 = *(const bf16x8*)(hb + ((size_t)ln<<10) + k0 + (quad<<3));
#pragma unroll
      for (int g = 0; g < 4; g++){
        bf16x8 b0 = *(const bf16x8*)(Wih1 + (size_t)((g<<10)+j0+ln)*1024 + k0 + (quad<<3));
        acc[g] = __builtin_amdgcn_mfma_f32_16x16x32_bf16(a0, b0, acc[g], 0, 0, 0);
        bf16x8 b1 = *(const bf16x8*)(Whh1 + (size_t)((g<<10)+j0+ln)*1024 + k0 + (quad<<3));
        acc[g] = __builtin_amdgcn_mfma_f32_16x16x32_bf16(a1, b1, acc[g], 0, 0, 0);
      }
    }
#pragma unroll
    for (int r = 0; r < 4; r++){
      int brow = (quad<<2)+r, j = j0+ln, ci = (brow<<10)+j;
      float i_ = acc[0][r], f_ = acc[1][r], z_ = acc[2][r], o_ = acc[3][r];
      float cp = c1[ci];
      float cn = sigmf(f_)*cp + expf(i_)*tanhf(z_);
      float hn = sigmf(o_)*tanhf(cn);
      c1[ci] = cn;
      h1seq[((size_t)t<<14) + ci] = (__bf16)hn;       // slot t1+1 = t
    }
  }
}

// ---------- residual + layernorm (writes x f32 and bf16 in place) ----------
__global__ __launch_bounds__(256) void ln_kernel(const float* __restrict__ y,
    float* __restrict__ x, __bf16* __restrict__ xbf,
    const float* __restrict__ g, const float* __restrict__ b){
  int row = blockIdx.x, tid = threadIdx.x, lane = tid&63, w = tid>>6;
  size_t base = (size_t)row<<10;
  int k = tid<<2;
  float4 yv = *(const float4*)(y + base + k);
  float4 xv = *(const float4*)(x + base + k);
  float4 u = { yv.x+xv.x, yv.y+xv.y, yv.z+xv.z, yv.w+xv.w };
  float s = u.x+u.y+u.z+u.w;
  float q = u.x*u.x + u.y*u.y + u.z*u.z + u.w*u.w;
  for (int off = 32; off > 0; off >>= 1){
    s += __shfl_down(s, off, 64);
    q += __shfl_down(q, off, 64);
  }
  __shared__ float ss[4], qq[4];
  if (lane == 0){ ss[w] = s; qq[w] = q; }
  __syncthreads();
  float ts = ss[0]+ss[1]+ss[2]+ss[3];
  float tq = qq[0]+qq[1]+qq[2]+qq[3];
  float mean = ts*(1.0f/1024.0f);
  float var  = tq*(1.0f/1024.0f) - mean*mean;
  float inv  = rsqrtf(var + 1e-5f);
  float4 gv = *(const float4*)(g + k);
  float4 bv = *(const float4*)(b + k);
  float4 o = { (u.x-mean)*inv*gv.x + bv.x, (u.y-mean)*inv*gv.y + bv.y,
               (u.z-mean)*inv*gv.z + bv.z, (u.w-mean)*inv*gv.w + bv.w };
  *(float4*)(x + base + k) = o;
  bf16x4 ob = { (__bf16)o.x, (__bf16)o.y, (__bf16)o.z, (__bf16)o.w };
  *(bf16x4*)(xbf + base + k) = ob;
}

extern "C" void kernel_launch(void* const* d_in, const int* in_sizes, int n_in,
                              void* d_out, int out_size, void* d_ws, size_t ws_size,
                              hipStream_t stream){
  const int*   seq = (const int*)d_in[0];
  const float* emb = (const float*)d_in[1];
  const float* Wih = (const float*)d_in[2];
  const float* Whh = (const float*)d_in[3];
  const float* bg  = (const float*)d_in[4];
  const float* pW  = (const float*)d_in[5];
  const float* pb  = (const float*)d_in[6];
  const float* lng = (const float*)d_in[7];
  const float* lnb = (const float*)d_in[8];
  const float* oW  = (const float*)d_in[9];
  const float* ob  = (const float*)d_in[10];
  float* out = (float*)d_out;

  char* ws = (char*)d_ws;
  size_t off = 0;
  auto alloc = [&](size_t bytes)->char*{
    char* p = ws + off; off += (bytes + 255) & ~(size_t)255; return p;
  };
  __bf16* wih_bf = (__bf16*)alloc(16777216ULL*2);   // [2][2][4096][1024]
  __bf16* whh_bf = (__bf16*)alloc(16777216ULL*2);
  __bf16* pw_bf  = (__bf16*)alloc(2097152ULL*2);    // [2][1024][1024]
  __bf16* ow_bf  = (__bf16*)alloc(32768000ULL*2);   // [32000][1024]
  float*  x      = (float*)alloc(4194304ULL*4);     // [4096][1024] f32
  __bf16* xbf    = (__bf16*)alloc(4194304ULL*2);
  float*  ihb    = (float*)alloc(16777216ULL*4);    // [256][16][4096] f32
  __bf16* h0seq  = (__bf16*)alloc(257ULL*16384*2);  // [257][16][1024]
  __bf16* h1seq  = (__bf16*)alloc(257ULL*16384*2);
  float*  c0     = (float*)alloc(16384ULL*4);
  float*  c1     = (float*)alloc(16384ULL*4);
  float*  y      = (float*)alloc(4194304ULL*4);     // [4096][1024] f32

  cvt_kernel<<<16384, 256, 0, stream>>>(Wih, wih_bf, 4194304);
  cvt_kernel<<<16384, 256, 0, stream>>>(Whh, whh_bf, 4194304);
  cvt_kernel<<<2048,  256, 0, stream>>>(pW,  pw_bf,  524288);
  cvt_kernel<<<32000, 256, 0, stream>>>(oW,  ow_bf,  8192000);
  gather_kernel<<<4096, 256, 0, stream>>>(seq, emb, x, xbf);
  hipMemsetAsync(h0seq, 0, 16384*2, stream);   // slot 0 = zeros (stays zero)
  hipMemsetAsync(h1seq, 0, 16384*2, stream);

  for (int blk = 0; blk < 2; blk++){
    const __bf16* wih0 = wih_bf + (size_t)blk*2*4194304;
    const __bf16* wih1 = wih0 + 4194304;
    const __bf16* whh0 = whh_bf + (size_t)blk*2*4194304;
    const __bf16* whh1 = whh0 + 4194304;
    const float*  bg0  = bg + blk*2*4096;
    const float*  bg1  = bg0 + 4096;
    // ih0 = x @ Wih0^T + bg0  (layer-0 input projection, parallel over S)
    gemm_kernel<<<dim3(64,64), 256, 0, stream>>>(xbf, wih0, bg0, ihb, 4096, 0);
    hipMemsetAsync(c0, 0, 16384*4, stream);
    hipMemsetAsync(c1, 0, 16384*4, stream);
    for (int t = 0; t <= 256; t++)
      tick_kernel<<<32, 256, 0, stream>>>(whh0, wih1, whh1, bg1, ihb, h0seq, h1seq, c0, c1, t);
    // y = gelu(h1 @ pW^T + pb); note h1seq+16384 is dense [4096][1024] row-major
    gemm_kernel<<<dim3(16,64), 256, 0, stream>>>(h1seq + 16384, pw_bf + (size_t)blk*1048576,
                                                 pb + blk*1024, y, 1024, 1);
    ln_kernel<<<4096, 256, 0, stream>>>(y, x, xbf, lng + blk*1024, lnb + blk*1024);
  }
  // logits = x @ out_W^T + out_b, remapped to [B,S,V]
  gemm_kernel<<<dim3(500,64), 256, 0, stream>>>(xbf, ow_bf, ob, out, 32000, 2);
}